// Round 1
// baseline (246.322 us; speedup 1.0000x reference)
//
#include <hip/hip_runtime.h>
#include <math.h>

// Problem constants (fixed by the reference setup_inputs): B=2, P=8192, K=16
#define PP    8192
#define NB    2
#define NPTS  16384          // NB * PP
#define KNN   16
#define EPSV  1e-17f

// ---- K1: brute-force exact 16-NN (self excluded) ----------------------------
// 64 queries per block (one per lane), 8 waves per block; each wave scans a
// stride-8 interleaved subset of the 8192 candidates from an LDS tile,
// maintaining a per-lane top-16 of 32-bit packed keys:
//   key = (ordered_float_bits(dist) & 0xFFFFE000) | candidate_idx   (idx < 8192)
// Branchless sorted insertion: new_k[j] = min(max(k[j-1], x), k[j]); k[0]=min(k[0],x)
// Partials merged through LDS by wave 0; exact dists recomputed from indices.

#define QPB   64
#define WPB   8
#define TPB   (WPB * 64)     // 512
#define TILE  TPB

__device__ __forceinline__ unsigned int umn(unsigned int a, unsigned int b) { return a < b ? a : b; }
__device__ __forceinline__ unsigned int umx(unsigned int a, unsigned int b) { return a > b ? a : b; }

__global__ __launch_bounds__(TPB) void knn_kernel(const float* __restrict__ pts,
                                                  int* __restrict__ out_idx,
                                                  float* __restrict__ out_dist) {
    __shared__ float4 tile[TILE];
    __shared__ unsigned int smerge[WPB * KNN * 64];

    const int lane = threadIdx.x & 63;
    const int wave = threadIdx.x >> 6;
    const int q0   = blockIdx.x * QPB;        // global query base (0..16383)
    const int b    = q0 >> 13;                // q0 / PP
    const int i    = (q0 & (PP - 1)) + lane;  // local query index within batch
    const float* bp = pts + (size_t)b * PP * 3;

    const float qx = bp[i * 3 + 0];
    const float qy = bp[i * 3 + 1];
    const float qz = bp[i * 3 + 2];
    const float d2q = qx * qx + qy * qy + qz * qz;

    unsigned int keys[KNN];
#pragma unroll
    for (int s = 0; s < KNN; ++s) keys[s] = 0xFFFFFFFFu;

    for (int t0 = 0; t0 < PP; t0 += TILE) {
        __syncthreads();
        {
            const int c = t0 + threadIdx.x;
            const float x = bp[c * 3 + 0];
            const float y = bp[c * 3 + 1];
            const float z = bp[c * 3 + 2];
            tile[threadIdx.x] = make_float4(x, y, z, x * x + y * y + z * z);
        }
        __syncthreads();
#pragma unroll 4
        for (int m = 0; m < TILE / WPB; ++m) {
            const int jt = wave + m * WPB;
            const float4 c4 = tile[jt];          // wave-uniform broadcast
            const int j = t0 + jt;
            const float dot = qx * c4.x + qy * c4.y + qz * c4.z;
            const float d = (d2q + c4.w) - (dot + dot);
            unsigned int u = __float_as_uint(d);
            u ^= (unsigned int)(((int)u) >> 31) | 0x80000000u;  // monotone float->uint
            unsigned int key = (u & 0xFFFFE000u) | (unsigned int)j;
            if (j == i) key = 0xFFFFFFFFu;       // exclude self
#pragma unroll
            for (int s = KNN - 1; s >= 1; --s) keys[s] = umn(umx(keys[s - 1], key), keys[s]);
            keys[0] = umn(keys[0], key);
        }
    }

    __syncthreads();
#pragma unroll
    for (int s = 0; s < KNN; ++s) smerge[(wave * KNN + s) * 64 + lane] = keys[s];
    __syncthreads();

    if (wave == 0) {
        for (int w = 1; w < WPB; ++w) {
#pragma unroll
            for (int s2 = 0; s2 < KNN; ++s2) {
                const unsigned int key = smerge[(w * KNN + s2) * 64 + lane];
#pragma unroll
                for (int s = KNN - 1; s >= 1; --s) keys[s] = umn(umx(keys[s - 1], key), keys[s]);
                keys[0] = umn(keys[0], key);
            }
        }
        const int q = q0 + lane;
#pragma unroll
        for (int s = 0; s < KNN; ++s) {
            const int j = (int)(keys[s] & 0x1FFFu);
            out_idx[q * KNN + s] = j;
            const float x = bp[j * 3 + 0];
            const float y = bp[j * 3 + 1];
            const float z = bp[j * 3 + 2];
            const float dot = qx * x + qy * y + qz * z;
            const float d = (d2q + (x * x + y * y + z * z)) - (dot + dot);
            out_dist[q * KNN + s] = fmaxf(d, 0.0f);   // ref clamps at 0
        }
    }
}

// ---- K2: phi weights + first denoise (n1) -----------------------------------
__global__ void denoise1_kernel(const float* __restrict__ normals,
                                const int* __restrict__ idx,
                                const float* __restrict__ dist,
                                float* __restrict__ phi_out,
                                float* __restrict__ n1_out) {
    const int q = blockIdx.x * blockDim.x + threadIdx.x;
    if (q >= NPTS) return;
    const int b = q >> 13;
    const float* bn = normals + (size_t)b * PP * 3;

    float d[KNN];
#pragma unroll
    for (int s = 0; s < KNN; ++s) d[s] = dist[q * KNN + s];
    float d1 = d[0];
#pragma unroll
    for (int s = 1; s < KNN; ++s) d1 = fminf(d1, d[s]);

    float s0 = d1 * 8.0f;                         // 2 * FILTER_SCALE^2 = 8
    const float sden = (s0 < EPSV) ? EPSV : s0;   // _eps_denom

    float sphi = 0.f, nx = 0.f, ny = 0.f, nz = 0.f;
#pragma unroll
    for (int s = 0; s < KNN; ++s) {
        float w = fmaxf(1.0f - d[s] / sden, 0.0f);
        float w2 = w * w;
        float ph = w2 * w2;
        phi_out[q * KNN + s] = ph;
        const int j = idx[q * KNN + s];
        nx += ph * bn[j * 3 + 0];
        ny += ph * bn[j * 3 + 1];
        nz += ph * bn[j * 3 + 2];
        sphi += ph;
    }
    const float den = (sphi < EPSV) ? EPSV : sphi;
    n1_out[q * 3 + 0] = nx / den;
    n1_out[q * 3 + 1] = ny / den;
    n1_out[q * 3 + 2] = nz / den;
}

// ---- K3: normal_w + second denoise (n2) -------------------------------------
__global__ void denoise2_kernel(const int* __restrict__ idx,
                                const float* __restrict__ phi,
                                const float* __restrict__ n1,
                                float* __restrict__ nw_out,
                                float* __restrict__ n2_out) {
    const int q = blockIdx.x * blockDim.x + threadIdx.x;
    if (q >= NPTS) return;
    const int b = q >> 13;
    const int gbase = b * PP;
    const float INV_SIG = 1.0f / (0.75f * 0.75f);

    const float ax = n1[q * 3 + 0];
    const float ay = n1[q * 3 + 1];
    const float az = n1[q * 3 + 2];
    const float an = fmaxf(sqrtf(ax * ax + ay * ay + az * az), 1e-12f);
    const float rx = ax / an, ry = ay / an, rz = az / an;

    float swn = 0.f, ox = 0.f, oy = 0.f, oz = 0.f;
#pragma unroll
    for (int s = 0; s < KNN; ++s) {
        const int j = idx[q * KNN + s];
        const float bx = n1[(gbase + j) * 3 + 0];
        const float by = n1[(gbase + j) * 3 + 1];
        const float bz = n1[(gbase + j) * 3 + 2];
        const float bnn = fmaxf(sqrtf(bx * bx + by * by + bz * bz), 1e-12f);
        const float ux = bx / bnn - rx;
        const float uy = by / bnn - ry;
        const float uz = bz / bnn - rz;
        const float dd = ux * ux + uy * uy + uz * uz;
        const float nw = expf(-dd * INV_SIG);
        nw_out[q * KNN + s] = nw;
        const float wk = phi[q * KNN + s] * nw;
        ox += wk * bx;                 // raw n1 (unnormalized), per reference
        oy += wk * by;
        oz += wk * bz;
        swn += wk;
    }
    const float den = (swn < EPSV) ? EPSV : swn;
    n2_out[q * 3 + 0] = ox / den;
    n2_out[q * 3 + 1] = oy / den;
    n2_out[q * 3 + 2] = oz / den;
}

// ---- K4: weights_proj + point-to-plane loss, per-block partial sums ---------
__global__ void loss_kernel(const float* __restrict__ pts,
                            const int* __restrict__ idx,
                            const float* __restrict__ dist,
                            const float* __restrict__ phi,
                            const float* __restrict__ nw,
                            const float* __restrict__ n2,
                            float* __restrict__ partial) {
    const int q = blockIdx.x * 64 + threadIdx.x;   // block = 64 (one wave)
    const int b = q >> 13;
    const int il = q & (PP - 1);
    const float* bp = pts + (size_t)b * PP * 3;
    const int gbase = b * PP;

    const float px = bp[il * 3 + 0];
    const float py = bp[il * 3 + 1];
    const float pz = bp[il * 3 + 2];

    float d[KNN];
#pragma unroll
    for (int s = 0; s < KNN; ++s) d[s] = dist[q * KNN + s];
    float d1 = d[0];
#pragma unroll
    for (int s = 1; s < KNN; ++s) d1 = fminf(d1, d[s]);
    const float thresh = 4.0f * d1;                // FILTER_SCALE * d1 * 2

    float num = 0.f, den = 0.f;
#pragma unroll
    for (int s = 0; s < KNN; ++s) {
        float w = phi[q * KNN + s] * nw[q * KNN + s];
        if (d[s] > thresh) w = 0.f;                // ball-query mask
        const int j = idx[q * KNN + s];
        const float nx = n2[(gbase + j) * 3 + 0];
        const float ny = n2[(gbase + j) * 3 + 1];
        const float nz = n2[(gbase + j) * 3 + 2];
        const float dts = (bp[j * 3 + 0] - px) * nx +
                          (bp[j * 3 + 1] - py) * ny +
                          (bp[j * 3 + 2] - pz) * nz;
        num += dts * dts * w;
        den += w;
    }
    const float dd = (den < EPSV) ? EPSV : den;
    float loss = num / dd;

#pragma unroll
    for (int off = 32; off >= 1; off >>= 1) loss += __shfl_down(loss, off, 64);
    if (threadIdx.x == 0) partial[blockIdx.x] = loss;
}

// ---- K5: final mean ---------------------------------------------------------
__global__ void finalize_kernel(const float* __restrict__ partial,
                                float* __restrict__ out) {
    // 64 threads, 256 partials
    float v = partial[threadIdx.x] + partial[threadIdx.x + 64] +
              partial[threadIdx.x + 128] + partial[threadIdx.x + 192];
#pragma unroll
    for (int off = 32; off >= 1; off >>= 1) v += __shfl_down(v, off, 64);
    if (threadIdx.x == 0) out[0] = v / (float)NPTS;
}

// ---- launch -----------------------------------------------------------------
extern "C" void kernel_launch(void* const* d_in, const int* in_sizes, int n_in,
                              void* d_out, int out_size, void* d_ws, size_t ws_size,
                              hipStream_t stream) {
    const float* points  = (const float*)d_in[0];   // (2, 8192, 3) f32
    const float* normals = (const float*)d_in[1];   // (2, 8192, 3) f32
    float* out = (float*)d_out;                     // scalar f32

    // workspace layout (floats): idx | dist | phi | nw | n1 | n2 | partials
    float* wsf    = (float*)d_ws;
    int*   w_idx  = (int*)wsf;                      // 16384*16 ints
    float* w_dist = wsf + 262144;                   // 16384*16
    float* w_phi  = wsf + 524288;                   // 16384*16
    float* w_nw   = wsf + 786432;                   // 16384*16
    float* w_n1   = wsf + 1048576;                  // 16384*3
    float* w_n2   = wsf + 1097728;                  // 16384*3
    float* w_part = wsf + 1146880;                  // 256

    knn_kernel<<<NPTS / QPB, TPB, 0, stream>>>(points, w_idx, w_dist);
    denoise1_kernel<<<NPTS / 256, 256, 0, stream>>>(normals, w_idx, w_dist, w_phi, w_n1);
    denoise2_kernel<<<NPTS / 256, 256, 0, stream>>>(w_idx, w_phi, w_n1, w_nw, w_n2);
    loss_kernel<<<NPTS / 64, 64, 0, stream>>>(points, w_idx, w_dist, w_phi, w_nw, w_n2, w_part);
    finalize_kernel<<<1, 64, 0, stream>>>(w_part, out);
}

// Round 2
// 178.784 us; speedup vs baseline: 1.3778x; 1.3778x over previous
//
#include <hip/hip_runtime.h>
#include <math.h>

// Problem constants (fixed by the reference setup_inputs): B=2, P=8192, K=16
#define PP    8192
#define NB    2
#define NPTS  16384          // NB * PP
#define KNN   16
#define EPSV  1e-17f

// ---- K1: brute-force exact 16-NN (self excluded) ----------------------------
// 64 queries per block (one per lane), 8 waves per block; each wave scans a
// stride-8 interleaved subset of the 8192 candidates from an LDS tile.
// Per-lane top-16 of FLOAT-packed keys:
//   d' = max(d, 0)  (sign bit 0 => uint order == float order)
//   key = as_float((bits(d') & 0xFFFFE000) | candidate_idx)   (idx < 8192)
// Sorted-insertion step uses the med3 identity (valid since keys[s-1]<=keys[s]):
//   new[s] = min(max(old[s-1], x), old[s]) == med3(old[s-1], x, old[s])
// -> one v_med3_f32 per slot (15) + one v_min_f32 for slot 0.
// Partials merged through LDS by wave 0; exact dists recomputed from indices.

#define QPB   64
#define WPB   8
#define TPB   (WPB * 64)     // 512
#define TILE  TPB

#define KEY_BIG 3.0e38f      // > any real key, finite (no NaN/inf in med3)

__global__ __launch_bounds__(TPB) void knn_kernel(const float* __restrict__ pts,
                                                  int* __restrict__ out_idx,
                                                  float* __restrict__ out_dist) {
    __shared__ float4 tile[TILE];
    __shared__ float smerge[WPB * KNN * 64];

    const int lane = threadIdx.x & 63;
    const int wave = threadIdx.x >> 6;
    const int q0   = blockIdx.x * QPB;        // global query base (0..16383)
    const int b    = q0 >> 13;                // q0 / PP
    const int i    = (q0 & (PP - 1)) + lane;  // local query index within batch
    const float* bp = pts + (size_t)b * PP * 3;

    const float qx = bp[i * 3 + 0];
    const float qy = bp[i * 3 + 1];
    const float qz = bp[i * 3 + 2];
    const float d2q = qx * qx + qy * qy + qz * qz;

    float keys[KNN];
#pragma unroll
    for (int s = 0; s < KNN; ++s) keys[s] = KEY_BIG;

    for (int t0 = 0; t0 < PP; t0 += TILE) {
        __syncthreads();
        {
            const int c = t0 + threadIdx.x;
            const float x = bp[c * 3 + 0];
            const float y = bp[c * 3 + 1];
            const float z = bp[c * 3 + 2];
            tile[threadIdx.x] = make_float4(x, y, z, x * x + y * y + z * z);
        }
        __syncthreads();
#pragma unroll 4
        for (int m = 0; m < TILE / WPB; ++m) {
            const int jt = wave + m * WPB;
            const float4 c4 = tile[jt];          // wave-uniform broadcast
            const int j = t0 + jt;
            const float dot = __builtin_fmaf(qz, c4.z,
                              __builtin_fmaf(qy, c4.y, qx * c4.x));
            const float d = __builtin_fmaf(-2.0f, dot, d2q + c4.w);
            const float dc = fmaxf(d, 0.0f);     // sign bit 0: float order == uint order
            unsigned int kb = (__float_as_uint(dc) & 0xFFFFE000u) | (unsigned int)j;
            float key = __uint_as_float(kb);
            if (j == i) key = KEY_BIG;           // exclude self (v_cndmask)
#pragma unroll
            for (int s = KNN - 1; s >= 1; --s)
                keys[s] = __builtin_amdgcn_fmed3f(keys[s - 1], key, keys[s]);
            keys[0] = fminf(keys[0], key);
        }
    }

    __syncthreads();
#pragma unroll
    for (int s = 0; s < KNN; ++s) smerge[(wave * KNN + s) * 64 + lane] = keys[s];
    __syncthreads();

    if (wave == 0) {
        for (int w = 1; w < WPB; ++w) {
#pragma unroll
            for (int s2 = 0; s2 < KNN; ++s2) {
                const float key = smerge[(w * KNN + s2) * 64 + lane];
#pragma unroll
                for (int s = KNN - 1; s >= 1; --s)
                    keys[s] = __builtin_amdgcn_fmed3f(keys[s - 1], key, keys[s]);
                keys[0] = fminf(keys[0], key);
            }
        }
        const int q = q0 + lane;
#pragma unroll
        for (int s = 0; s < KNN; ++s) {
            const int j = (int)(__float_as_uint(keys[s]) & 0x1FFFu);
            out_idx[q * KNN + s] = j;
            const float x = bp[j * 3 + 0];
            const float y = bp[j * 3 + 1];
            const float z = bp[j * 3 + 2];
            const float dot = qx * x + qy * y + qz * z;
            const float d = (d2q + (x * x + y * y + z * z)) - (dot + dot);
            out_dist[q * KNN + s] = fmaxf(d, 0.0f);   // ref clamps at 0
        }
    }
}

// ---- K2: phi weights + first denoise (n1) -----------------------------------
__global__ void denoise1_kernel(const float* __restrict__ normals,
                                const int* __restrict__ idx,
                                const float* __restrict__ dist,
                                float* __restrict__ phi_out,
                                float* __restrict__ n1_out) {
    const int q = blockIdx.x * blockDim.x + threadIdx.x;
    if (q >= NPTS) return;
    const int b = q >> 13;
    const float* bn = normals + (size_t)b * PP * 3;

    float d[KNN];
#pragma unroll
    for (int s = 0; s < KNN; ++s) d[s] = dist[q * KNN + s];
    float d1 = d[0];
#pragma unroll
    for (int s = 1; s < KNN; ++s) d1 = fminf(d1, d[s]);

    float s0 = d1 * 8.0f;                         // 2 * FILTER_SCALE^2 = 8
    const float sden = (s0 < EPSV) ? EPSV : s0;   // _eps_denom

    float sphi = 0.f, nx = 0.f, ny = 0.f, nz = 0.f;
#pragma unroll
    for (int s = 0; s < KNN; ++s) {
        float w = fmaxf(1.0f - d[s] / sden, 0.0f);
        float w2 = w * w;
        float ph = w2 * w2;
        phi_out[q * KNN + s] = ph;
        const int j = idx[q * KNN + s];
        nx += ph * bn[j * 3 + 0];
        ny += ph * bn[j * 3 + 1];
        nz += ph * bn[j * 3 + 2];
        sphi += ph;
    }
    const float den = (sphi < EPSV) ? EPSV : sphi;
    n1_out[q * 3 + 0] = nx / den;
    n1_out[q * 3 + 1] = ny / den;
    n1_out[q * 3 + 2] = nz / den;
}

// ---- K3: normal_w + second denoise (n2) -------------------------------------
__global__ void denoise2_kernel(const int* __restrict__ idx,
                                const float* __restrict__ phi,
                                const float* __restrict__ n1,
                                float* __restrict__ nw_out,
                                float* __restrict__ n2_out) {
    const int q = blockIdx.x * blockDim.x + threadIdx.x;
    if (q >= NPTS) return;
    const int b = q >> 13;
    const int gbase = b * PP;
    const float INV_SIG = 1.0f / (0.75f * 0.75f);

    const float ax = n1[q * 3 + 0];
    const float ay = n1[q * 3 + 1];
    const float az = n1[q * 3 + 2];
    const float an = fmaxf(sqrtf(ax * ax + ay * ay + az * az), 1e-12f);
    const float rx = ax / an, ry = ay / an, rz = az / an;

    float swn = 0.f, ox = 0.f, oy = 0.f, oz = 0.f;
#pragma unroll
    for (int s = 0; s < KNN; ++s) {
        const int j = idx[q * KNN + s];
        const float bx = n1[(gbase + j) * 3 + 0];
        const float by = n1[(gbase + j) * 3 + 1];
        const float bz = n1[(gbase + j) * 3 + 2];
        const float bnn = fmaxf(sqrtf(bx * bx + by * by + bz * bz), 1e-12f);
        const float ux = bx / bnn - rx;
        const float uy = by / bnn - ry;
        const float uz = bz / bnn - rz;
        const float dd = ux * ux + uy * uy + uz * uz;
        const float nw = expf(-dd * INV_SIG);
        nw_out[q * KNN + s] = nw;
        const float wk = phi[q * KNN + s] * nw;
        ox += wk * bx;                 // raw n1 (unnormalized), per reference
        oy += wk * by;
        oz += wk * bz;
        swn += wk;
    }
    const float den = (swn < EPSV) ? EPSV : swn;
    n2_out[q * 3 + 0] = ox / den;
    n2_out[q * 3 + 1] = oy / den;
    n2_out[q * 3 + 2] = oz / den;
}

// ---- K4: weights_proj + point-to-plane loss, per-block partial sums ---------
__global__ void loss_kernel(const float* __restrict__ pts,
                            const int* __restrict__ idx,
                            const float* __restrict__ dist,
                            const float* __restrict__ phi,
                            const float* __restrict__ nw,
                            const float* __restrict__ n2,
                            float* __restrict__ partial) {
    const int q = blockIdx.x * 64 + threadIdx.x;   // block = 64 (one wave)
    const int b = q >> 13;
    const int il = q & (PP - 1);
    const float* bp = pts + (size_t)b * PP * 3;
    const int gbase = b * PP;

    const float px = bp[il * 3 + 0];
    const float py = bp[il * 3 + 1];
    const float pz = bp[il * 3 + 2];

    float d[KNN];
#pragma unroll
    for (int s = 0; s < KNN; ++s) d[s] = dist[q * KNN + s];
    float d1 = d[0];
#pragma unroll
    for (int s = 1; s < KNN; ++s) d1 = fminf(d1, d[s]);
    const float thresh = 4.0f * d1;                // FILTER_SCALE * d1 * 2

    float num = 0.f, den = 0.f;
#pragma unroll
    for (int s = 0; s < KNN; ++s) {
        float w = phi[q * KNN + s] * nw[q * KNN + s];
        if (d[s] > thresh) w = 0.f;                // ball-query mask
        const int j = idx[q * KNN + s];
        const float nx = n2[(gbase + j) * 3 + 0];
        const float ny = n2[(gbase + j) * 3 + 1];
        const float nz = n2[(gbase + j) * 3 + 2];
        const float dts = (bp[j * 3 + 0] - px) * nx +
                          (bp[j * 3 + 1] - py) * ny +
                          (bp[j * 3 + 2] - pz) * nz;
        num += dts * dts * w;
        den += w;
    }
    const float dd = (den < EPSV) ? EPSV : den;
    float loss = num / dd;

#pragma unroll
    for (int off = 32; off >= 1; off >>= 1) loss += __shfl_down(loss, off, 64);
    if (threadIdx.x == 0) partial[blockIdx.x] = loss;
}

// ---- K5: final mean ---------------------------------------------------------
__global__ void finalize_kernel(const float* __restrict__ partial,
                                float* __restrict__ out) {
    // 64 threads, 256 partials
    float v = partial[threadIdx.x] + partial[threadIdx.x + 64] +
              partial[threadIdx.x + 128] + partial[threadIdx.x + 192];
#pragma unroll
    for (int off = 32; off >= 1; off >>= 1) v += __shfl_down(v, off, 64);
    if (threadIdx.x == 0) out[0] = v / (float)NPTS;
}

// ---- launch -----------------------------------------------------------------
extern "C" void kernel_launch(void* const* d_in, const int* in_sizes, int n_in,
                              void* d_out, int out_size, void* d_ws, size_t ws_size,
                              hipStream_t stream) {
    const float* points  = (const float*)d_in[0];   // (2, 8192, 3) f32
    const float* normals = (const float*)d_in[1];   // (2, 8192, 3) f32
    float* out = (float*)d_out;                     // scalar f32

    // workspace layout (floats): idx | dist | phi | nw | n1 | n2 | partials
    float* wsf    = (float*)d_ws;
    int*   w_idx  = (int*)wsf;                      // 16384*16 ints
    float* w_dist = wsf + 262144;                   // 16384*16
    float* w_phi  = wsf + 524288;                   // 16384*16
    float* w_nw   = wsf + 786432;                   // 16384*16
    float* w_n1   = wsf + 1048576;                  // 16384*3
    float* w_n2   = wsf + 1097728;                  // 16384*3
    float* w_part = wsf + 1146880;                  // 256

    knn_kernel<<<NPTS / QPB, TPB, 0, stream>>>(points, w_idx, w_dist);
    denoise1_kernel<<<NPTS / 256, 256, 0, stream>>>(normals, w_idx, w_dist, w_phi, w_n1);
    denoise2_kernel<<<NPTS / 256, 256, 0, stream>>>(w_idx, w_phi, w_n1, w_nw, w_n2);
    loss_kernel<<<NPTS / 64, 64, 0, stream>>>(points, w_idx, w_dist, w_phi, w_nw, w_n2, w_part);
    finalize_kernel<<<1, 64, 0, stream>>>(w_part, out);
}